// Round 9
// baseline (944.290 us; speedup 1.0000x reference)
//
#include <hip/hip_runtime.h>
#include <hip/hip_bf16.h>
#include <stdint.h>

#define N_NODES 100000
#define MT      782          // 128-row stripes
#define MPAD    (MT*128)     // 100096
#define IN_DIM  2048
#define HID     512
#define OUTD    128
#define NG      512
#define LOG2F_  0.69314718055994531f

typedef __attribute__((ext_vector_type(4))) float f32x4;
typedef __attribute__((ext_vector_type(8))) short bf16x8;

typedef const __attribute__((address_space(1))) unsigned int gas_u32;
typedef __attribute__((address_space(3))) unsigned int las_u32;

__device__ __forceinline__ void gload_lds16(const void* g, void* lds) {
  __builtin_amdgcn_global_load_lds((gas_u32*)g, (las_u32*)lds, 16, 0, 0);
}

__device__ __forceinline__ short f2bf(float f) {   // manual RNE
  unsigned u = __builtin_bit_cast(unsigned, f);
  u = (u + 0x7fffu + ((u >> 16) & 1u)) >> 16;
  return (short)u;
}
__device__ __forceinline__ short f2bf_hw(float f) {  // hot loop: hw cvt
  __hip_bfloat16 h = __float2bfloat16(f);
  return __builtin_bit_cast(short, h);
}
__device__ __forceinline__ float bf2f(short s) {
  unsigned u = ((unsigned)(unsigned short)s) << 16;
  return __builtin_bit_cast(float, u);
}

__device__ __forceinline__ f32x4 mfma16(bf16x8 a, bf16x8 b, f32x4 c) {
  return __builtin_amdgcn_mfma_f32_16x16x32_bf16(a, b, c, 0, 0, 0);
}

// ---------------- prep: transpose+cast weights to bf16 B^T (row-major) -------
__global__ void kprep(const float* __restrict__ W1, const float* __restrict__ Wj,
                      const float* __restrict__ W2, const float* __restrict__ W3,
                      const float* __restrict__ ge,
                      short* __restrict__ wcat, short* __restrict__ w2t,
                      short* __restrict__ w3t, short* __restrict__ gencb) {
  const int S1 = 640 * 2048, S2 = 512 * 512, S3 = 128 * 512, S4 = 512 * 128;
  int t = blockIdx.x * 256 + threadIdx.x;
  if (t < S1) {
    int n = t >> 11, k = t & 2047;
    float v = (n < 512) ? W1[(size_t)k * 512 + n] : Wj[(size_t)k * 128 + (n - 512)];
    wcat[t] = f2bf(v);
  } else {
    t -= S1;
    if (t < S2) {
      int n = t >> 9, k = t & 511;
      w2t[t] = f2bf(W2[(size_t)k * 512 + n]);
    } else {
      t -= S2;
      if (t < S3) {
        int n = t >> 9, k = t & 511;
        w3t[t] = f2bf(W3[(size_t)k * 128 + n]);
      } else {
        t -= S3;
        if (t < S4) gencb[t] = f2bf(ge[t]);
      }
    }
  }
}

// ---- K1: 128x256 tile, 256 thr / 4 waves (2Mw x 2Nw, wave 64x128), BK=32.
// R1 engine (2-barrier stage->sync->compute, 2 blocks/CU) + fat-N for traffic.
// nt in {0,1}: cols nt*256 -> h1 (relu+b1). nt==2: 128-wide -> jump (+b3+bj).
// A staged f32 via gload_lds (cvt at frag-read on idle VALU); B via gload_lds
// (wcat 2.6MB, L2-resident). k-slot-major LDS layouts, conflict-free (R6/R7).
// Grid: bid = r*24 + nt*8 + x -> stripe s = r*8+x: the 3 nt-siblings of a
// stripe land on the SAME XCD concurrently -> A-tile fetched once into L2.
__global__ __launch_bounds__(256, 2) void k1(
    const float* __restrict__ feat, const short* __restrict__ wcat,
    const float* __restrict__ b1, const float* __restrict__ b3,
    const float* __restrict__ bj,
    short* __restrict__ h1, short* __restrict__ jmp) {
  __shared__ __align__(16) char L[32768];  // A f32 [8][128][4] @0 (16KB); B bf16 [4][NW][8] @16384
  const int tid = threadIdx.x;
  const int lane = tid & 63, w = tid >> 6;
  const int l16 = lane & 15, lh = lane >> 4;
  const int mw = w >> 1, nw = w & 1;
  const int bid = blockIdx.x;
  const int r = bid / 24, w24 = bid - r * 24, nt = w24 >> 3, x = w24 & 7;
  const int s = r * 8 + x;
  if (s >= MT) return;
  const int m0 = s * 128;
  const int NW = (nt == 2) ? 128 : 256;        // B tile width
  const int NF = NW >> 5;                       // frags per wave (8 or 4)
  const int n0 = nt * 256;                      // nt==2 -> 512

  f32x4 acc[4][8];
#pragma unroll
  for (int m = 0; m < 4; m++)
#pragma unroll
    for (int n = 0; n < 8; n++) acc[m][n] = (f32x4){0.f, 0.f, 0.f, 0.f};

  // A staging: 1024 16B units, u = i*256+tid -> ks=u>>7 (0..7), row=u&127
  const float* asrc[4];
  int adst[4];
#pragma unroll
  for (int i = 0; i < 4; i++) {
    int u = i * 256 + tid;
    int row = u & 127, ks = u >> 7;
    int rowg = m0 + row;
    if (rowg >= N_NODES) rowg = N_NODES - 1;  // clamp; masked via gid=-1 in k3
    asrc[i] = feat + (size_t)rowg * IN_DIM + ks * 4;
    adst[i] = u * 16;
  }
  // B staging: NW*4 16B units, u = i*256+tid -> ks2=u/NW, n=u%NW (NW pow2)
  const int lnw = (nt == 2) ? 7 : 8;
  const int nbi = NW >> 6;                      // issues per thread (4 or 2)
  const short* bsrc[4];
  int bdst[4];
#pragma unroll
  for (int i = 0; i < 4; i++) {
    if (i < nbi) {
      int u = i * 256 + tid;
      int ks2 = u >> lnw, n = u & (NW - 1);
      bsrc[i] = wcat + (size_t)(n0 + n) * IN_DIM + ks2 * 8;
      bdst[i] = 16384 + u * 16;
    } else { bsrc[i] = nullptr; bdst[i] = 0; }
  }

  const int a_rd = (mw * 64 + l16) * 16;        // + (2lh+h)*2048, + m*256
  const int b_rd = 16384 + (lh * NW + nw * (NW >> 1) + l16) * 16;  // + j*256

  for (int kt = 0; kt < IN_DIM / 32; ++kt) {
    __syncthreads();  // bar1: previous compute's LDS reads done
#pragma unroll
    for (int i = 0; i < 4; i++) gload_lds16(asrc[i] + kt * 32, L + adst[i]);
#pragma unroll
    for (int i = 0; i < 4; i++)
      if (i < nbi) gload_lds16(bsrc[i] + kt * 32, L + bdst[i]);
    __syncthreads();  // bar2: staging visible (drain covered by sibling block)
    bf16x8 b[8];
#pragma unroll
    for (int j = 0; j < 8; j++)
      if (j < NF) b[j] = *(const bf16x8*)(L + b_rd + j * 256);
#pragma unroll
    for (int m = 0; m < 4; m++) {
      f32x4 lo = *(const f32x4*)(L + (2 * lh) * 2048 + a_rd + m * 256);
      f32x4 hi = *(const f32x4*)(L + (2 * lh + 1) * 2048 + a_rd + m * 256);
      bf16x8 a;
#pragma unroll
      for (int q = 0; q < 4; q++) { a[q] = f2bf_hw(lo[q]); a[q + 4] = f2bf_hw(hi[q]); }
#pragma unroll
      for (int j = 0; j < 8; j++)
        if (j < NF) acc[m][j] = mfma16(a, b[j], acc[m][j]);
    }
  }

  if (nt < 2) {
#pragma unroll
    for (int j = 0; j < 8; j++) {
      const int c = n0 + nw * 128 + j * 16 + l16;
      const float bias = b1[c];
#pragma unroll
      for (int m = 0; m < 4; m++) {
        const int row = m0 + mw * 64 + m * 16 + lh * 4;
#pragma unroll
        for (int rr = 0; rr < 4; rr++) {
          float v = acc[m][j][rr] + bias;
          v = v > 0.f ? v : 0.f;
          h1[(size_t)(row + rr) * HID + c] = f2bf(v);
        }
      }
    }
  } else {
#pragma unroll
    for (int j = 0; j < 4; j++) {
      const int cj = nw * 64 + j * 16 + l16;
      const float bias = b3[cj] + bj[cj];
#pragma unroll
      for (int m = 0; m < 4; m++) {
        const int row = m0 + mw * 64 + m * 16 + lh * 4;
#pragma unroll
        for (int rr = 0; rr < 4; rr++)
          jmp[(size_t)(row + rr) * OUTD + cj] = f2bf(acc[m][j][rr] + bias);
      }
    }
  }
}

// ---- K2: same skeleton, 128x256, nt in {0,1}. h1(bf16) @ W2^T -> h2 (relu+b2).
__global__ __launch_bounds__(256, 2) void k2(
    const short* __restrict__ h1, const short* __restrict__ w2t,
    const float* __restrict__ b2, short* __restrict__ h2) {
  __shared__ __align__(16) char L[24576];  // A bf16 [4][128][8] @0 (8KB); B [4][256][8] @8192
  const int tid = threadIdx.x;
  const int lane = tid & 63, w = tid >> 6;
  const int l16 = lane & 15, lh = lane >> 4;
  const int mw = w >> 1, nw = w & 1;
  const int bid = blockIdx.x;
  const int r = bid >> 4, nt = (bid >> 3) & 1, x = bid & 7;
  const int s = r * 8 + x;
  if (s >= MT) return;
  const int m0 = s * 128, n0 = nt * 256;

  f32x4 acc[4][8];
#pragma unroll
  for (int m = 0; m < 4; m++)
#pragma unroll
    for (int n = 0; n < 8; n++) acc[m][n] = (f32x4){0.f, 0.f, 0.f, 0.f};

  // A: 512 units: u = i*256+tid (i<2) -> ks2=u>>7, row=u&127
  const short* asrc[2];
  int adst[2];
#pragma unroll
  for (int i = 0; i < 2; i++) {
    int u = i * 256 + tid;
    asrc[i] = h1 + (size_t)(m0 + (u & 127)) * HID + (u >> 7) * 8;
    adst[i] = u * 16;
  }
  // B: 1024 units: u = i*256+tid -> ks2=u>>8, n=u&255
  const short* bsrc[4];
  int bdst[4];
#pragma unroll
  for (int i = 0; i < 4; i++) {
    int u = i * 256 + tid;
    bsrc[i] = w2t + (size_t)(n0 + (u & 255)) * HID + (u >> 8) * 8;
    bdst[i] = 8192 + u * 16;
  }

  const int a_rd = (lh * 128 + mw * 64 + l16) * 16;          // + m*256
  const int b_rd = 8192 + (lh * 256 + nw * 128 + l16) * 16;  // + j*256

  for (int kt = 0; kt < HID / 32; ++kt) {
    __syncthreads();
#pragma unroll
    for (int i = 0; i < 2; i++) gload_lds16(asrc[i] + kt * 32, L + adst[i]);
#pragma unroll
    for (int i = 0; i < 4; i++) gload_lds16(bsrc[i] + kt * 32, L + bdst[i]);
    __syncthreads();
    bf16x8 b[8];
#pragma unroll
    for (int j = 0; j < 8; j++) b[j] = *(const bf16x8*)(L + b_rd + j * 256);
#pragma unroll
    for (int m = 0; m < 4; m++) {
      bf16x8 a = *(const bf16x8*)(L + a_rd + m * 256);
#pragma unroll
      for (int j = 0; j < 8; j++) acc[m][j] = mfma16(a, b[j], acc[m][j]);
    }
  }

#pragma unroll
  for (int j = 0; j < 8; j++) {
    const int c = n0 + nw * 128 + j * 16 + l16;
    const float bias = b2[c];
#pragma unroll
    for (int m = 0; m < 4; m++) {
      const int row = m0 + mw * 64 + m * 16 + lh * 4;
#pragma unroll
      for (int rr = 0; rr < 4; rr++) {
        float v = acc[m][j][rr] + bias;
        v = v > 0.f ? v : 0.f;
        h2[(size_t)(row + rr) * HID + c] = f2bf(v);
      }
    }
  }
}

// ---------------- K3: l_enc = h2@W3^T + jump; res = l_enc@g_enc^T; JS loss ----
__global__ __launch_bounds__(256, 2) void k3(
    const short* __restrict__ h2, const short* __restrict__ w3t,
    const short* __restrict__ jmp, const short* __restrict__ genc,
    const int* __restrict__ gid, float* __restrict__ partials) {
  __shared__ __align__(16) short As[128 * 32];
  __shared__ __align__(16) short Bs[128 * 32];
  __shared__ __align__(16) short Ll[128 * 128];  // l_enc, XOR-swizzled rows
  __shared__ int gids[128];
  __shared__ float sred[8];
  const int mt = blockIdx.x;
  const int m0 = mt * 128;
  const int tid = threadIdx.x;
  const int lane = tid & 63, wid = tid >> 6;
  const int wr = wid >> 1, wc = wid & 1;
  const int l16 = lane & 15, lh = lane >> 4;

  if (tid < 128) {
    int r = m0 + tid;
    gids[tid] = (r < N_NODES) ? gid[r] : -1;
  }

  f32x4 acc[4][4];
#pragma unroll
  for (int i = 0; i < 4; i++)
#pragma unroll
    for (int j = 0; j < 4; j++) acc[i][j] = (f32x4){0.f, 0.f, 0.f, 0.f};

  const short* ap0 = h2 + (size_t)(m0 + (tid >> 2)) * HID + (tid & 3) * 8;
  const short* ap1 = ap0 + (size_t)64 * HID;
  const short* bp0 = w3t + (size_t)(tid >> 2) * HID + (tid & 3) * 8;
  const short* bp1 = bp0 + (size_t)64 * HID;

  for (int kt = 0; kt < HID / 32; ++kt) {
    __syncthreads();
    gload_lds16(ap0 + kt * 32, &As[tid * 8]);
    gload_lds16(ap1 + kt * 32, &As[tid * 8 + 2048]);
    gload_lds16(bp0 + kt * 32, &Bs[tid * 8]);
    gload_lds16(bp1 + kt * 32, &Bs[tid * 8 + 2048]);
    __syncthreads();
    bf16x8 a[4], b[4];
#pragma unroll
    for (int i = 0; i < 4; i++)
      a[i] = *(const bf16x8*)(&As[(wr * 64 + i * 16 + l16) * 32 + lh * 8]);
#pragma unroll
    for (int j = 0; j < 4; j++)
      b[j] = *(const bf16x8*)(&Bs[(wc * 64 + j * 16 + l16) * 32 + lh * 8]);
#pragma unroll
    for (int i = 0; i < 4; i++)
#pragma unroll
      for (int j = 0; j < 4; j++) acc[i][j] = mfma16(a[i], b[j], acc[i][j]);
  }

  // epilogue: l_enc = acc + jump (jump already holds b3+bj) -> Ll (swizzled)
#pragma unroll
  for (int j = 0; j < 4; j++) {
    const int col = wc * 64 + j * 16 + l16;
#pragma unroll
    for (int i = 0; i < 4; i++) {
      const int rowb = wr * 64 + i * 16 + lh * 4;
#pragma unroll
      for (int r = 0; r < 4; r++) {
        const int row = rowb + r;
        float v = acc[i][j][r] + bf2f(jmp[(size_t)(m0 + row) * OUTD + col]);
        unsigned byte = (unsigned)row * 256u +
                        (((unsigned)col * 2u) ^ (((unsigned)(row & 7)) << 4));
        *(short*)((char*)Ll + byte) = f2bf(v);
      }
    }
  }
  __syncthreads();

  int myg[4][4];
#pragma unroll
  for (int i = 0; i < 4; i++)
#pragma unroll
    for (int r = 0; r < 4; r++) myg[i][r] = gids[wr * 64 + i * 16 + lh * 4 + r];

  float pacc = 0.f, nacc = 0.f;
  for (int nc = 0; nc < 4; ++nc) {
    f32x4 a2[4][4];
#pragma unroll
    for (int i = 0; i < 4; i++)
#pragma unroll
      for (int j = 0; j < 4; j++) a2[i][j] = (f32x4){0.f, 0.f, 0.f, 0.f};
#pragma unroll
    for (int ks = 0; ks < 4; ++ks) {
      bf16x8 af[4], bg[4];
#pragma unroll
      for (int i = 0; i < 4; i++) {
        const int row = wr * 64 + i * 16 + l16;
        unsigned byte = (unsigned)row * 256u +
                        (((unsigned)(ks * 64 + lh * 16)) ^ (((unsigned)(row & 7)) << 4));
        af[i] = *(const bf16x8*)((const char*)Ll + byte);
      }
#pragma unroll
      for (int j = 0; j < 4; j++) {
        const int g = nc * 128 + wc * 64 + j * 16 + l16;
        bg[j] = *(const bf16x8*)(genc + (size_t)g * OUTD + ks * 32 + lh * 8);
      }
#pragma unroll
      for (int i = 0; i < 4; i++)
#pragma unroll
        for (int j = 0; j < 4; j++) a2[i][j] = mfma16(af[i], bg[j], a2[i][j]);
    }
#pragma unroll
    for (int j = 0; j < 4; j++) {
      const int g = nc * 128 + wc * 64 + j * 16 + l16;
#pragma unroll
      for (int i = 0; i < 4; i++) {
#pragma unroll
        for (int r = 0; r < 4; r++) {
          float rv = a2[i][j][r];
          int gr = myg[i][r];
          float t = __expf(-fabsf(rv));
          float lg = __logf(1.f + t);
          if (gr == g)
            pacc += LOG2F_ - (fmaxf(-rv, 0.f) + lg);
          else if (gr >= 0)
            nacc += (fmaxf(rv, 0.f) + lg) - LOG2F_;
        }
      }
    }
  }

#pragma unroll
  for (int o = 32; o; o >>= 1) {
    pacc += __shfl_down(pacc, o);
    nacc += __shfl_down(nacc, o);
  }
  if (lane == 0) { sred[wid] = pacc; sred[4 + wid] = nacc; }
  __syncthreads();
  if (tid == 0) {
    partials[2 * mt] = sred[0] + sred[1] + sred[2] + sred[3];
    partials[2 * mt + 1] = sred[4] + sred[5] + sred[6] + sred[7];
  }
}

// ---------------- K4: deterministic final reduction ---------------------------
__global__ void k4(const float* __restrict__ partials, float* __restrict__ out) {
  const int tid = threadIdx.x;
  float p = 0.f, n = 0.f;
  for (int i = tid; i < MT; i += 256) {
    p += partials[2 * i];
    n += partials[2 * i + 1];
  }
#pragma unroll
  for (int o = 32; o; o >>= 1) {
    p += __shfl_down(p, o);
    n += __shfl_down(n, o);
  }
  __shared__ float sp[4], sn[4];
  const int wid = tid >> 6, lane = tid & 63;
  if (lane == 0) { sp[wid] = p; sn[wid] = n; }
  __syncthreads();
  if (tid == 0) {
    float P = sp[0] + sp[1] + sp[2] + sp[3];
    float Nn = sn[0] + sn[1] + sn[2] + sn[3];
    out[0] = Nn / (100000.0f * 511.0f) - P / 100000.0f;
  }
}

extern "C" void kernel_launch(void* const* d_in, const int* in_sizes, int n_in,
                              void* d_out, int out_size, void* d_ws, size_t ws_size,
                              hipStream_t stream) {
  const float* feat = (const float*)d_in[0];
  const float* genc_f = (const float*)d_in[1];
  const int* gid = (const int*)d_in[2];
  const float* W1 = (const float*)d_in[3];
  const float* b1 = (const float*)d_in[4];
  const float* W2 = (const float*)d_in[5];
  const float* b2 = (const float*)d_in[6];
  const float* W3 = (const float*)d_in[7];
  const float* b3 = (const float*)d_in[8];
  const float* Wj = (const float*)d_in[9];
  const float* bj = (const float*)d_in[10];
  float* out = (float*)d_out;

  char* ws = (char*)d_ws;
  float* partials = (float*)ws;                       // 782*2 f32
  short* wcat = (short*)(ws + 8192);                  // [640][2048] bf16 row-major
  short* w2t = wcat + (size_t)640 * 2048;             // [512][512]
  short* w3t = w2t + (size_t)512 * 512;               // [128][512]
  short* gencb = w3t + (size_t)128 * 512;             // [512][128]
  short* h1 = gencb + (size_t)512 * 128;              // [MPAD][512]
  short* h2 = h1 + (size_t)MPAD * 512;                // [MPAD][512]
  short* jmp = h2 + (size_t)MPAD * 512;               // [MPAD][128]

  kprep<<<6656, 256, 0, stream>>>(W1, Wj, W2, W3, genc_f, wcat, w2t, w3t, gencb);
  k1<<<98 * 24, 256, 0, stream>>>(feat, wcat, b1, b3, bj, h1, jmp);
  k2<<<98 * 16, 256, 0, stream>>>(h1, w2t, b2, h2);
  k3<<<MT, 256, 0, stream>>>(h2, w3t, jmp, gencb, gid, partials);
  k4<<<1, 256, 0, stream>>>(partials, out);
}

// Round 10
// 669.858 us; speedup vs baseline: 1.4097x; 1.4097x over previous
//
#include <hip/hip_runtime.h>
#include <hip/hip_bf16.h>
#include <stdint.h>

#define N_NODES 100000
#define MT      782          // 128-row stripes
#define MPAD    (MT*128)     // 100096
#define IN_DIM  2048
#define HID     512
#define OUTD    128
#define NG      512
#define LOG2F_  0.69314718055994531f

typedef __attribute__((ext_vector_type(4))) float f32x4;
typedef __attribute__((ext_vector_type(8))) short bf16x8;

typedef const __attribute__((address_space(1))) unsigned int gas_u32;
typedef __attribute__((address_space(3))) unsigned int las_u32;

__device__ __forceinline__ void gload_lds16(const void* g, void* lds) {
  __builtin_amdgcn_global_load_lds((gas_u32*)g, (las_u32*)lds, 16, 0, 0);
}

__device__ __forceinline__ short f2bf(float f) {   // manual RNE
  unsigned u = __builtin_bit_cast(unsigned, f);
  u = (u + 0x7fffu + ((u >> 16) & 1u)) >> 16;
  return (short)u;
}
__device__ __forceinline__ short f2bf_hw(float f) {
  __hip_bfloat16 h = __float2bfloat16(f);
  return __builtin_bit_cast(short, h);
}
__device__ __forceinline__ float bf2f(short s) {
  unsigned u = ((unsigned)(unsigned short)s) << 16;
  return __builtin_bit_cast(float, u);
}

__device__ __forceinline__ f32x4 mfma16(bf16x8 a, bf16x8 b, f32x4 c) {
  return __builtin_amdgcn_mfma_f32_16x16x32_bf16(a, b, c, 0, 0, 0);
}

// ---------------- prep ---------------------------------------------------------
// wcatS: k-slot global layout [k/8][n(640)][e=k%8] -> linear gload_lds staging of
//        a 128-col group lands k-slot-major in LDS with coalesced sources (m173).
// w2tS : same for W2, n=512.  w3t: row-major [n][k].  gencb: row-major [g][k].
__global__ void kprep(const float* __restrict__ W1, const float* __restrict__ Wj,
                      const float* __restrict__ W2, const float* __restrict__ W3,
                      const float* __restrict__ ge,
                      short* __restrict__ wcatS, short* __restrict__ w2tS,
                      short* __restrict__ w3t, short* __restrict__ gencb) {
  const int S1 = 640 * 2048, S2 = 512 * 512, S3 = 128 * 512, S4 = 512 * 128;
  int t = blockIdx.x * 256 + threadIdx.x;
  if (t < S1) {
    int e = t & 7, rest = t >> 3;
    int n = rest % 640, kb = rest / 640;
    int k = kb * 8 + e;
    float v = (n < 512) ? W1[(size_t)k * 512 + n] : Wj[(size_t)k * 128 + (n - 512)];
    wcatS[t] = f2bf(v);
  } else {
    t -= S1;
    if (t < S2) {
      int e = t & 7, rest = t >> 3;
      int n = rest & 511, kb = rest >> 9;
      int k = kb * 8 + e;
      w2tS[t] = f2bf(W2[(size_t)k * 512 + n]);
    } else {
      t -= S2;
      if (t < S3) {
        int n = t >> 9, k = t & 511;
        w3t[t] = f2bf(W3[(size_t)k * 128 + n]);
      } else {
        t -= S3;
        if (t < S4) gencb[t] = f2bf(ge[t]);
      }
    }
  }
}

// ---- K1: R1 engine + XCD-sibling grid + conflict-free k-slot LDS.
// 128x128 tile, 256 thr / 4 waves (2x2), BK=32, single-buf 16KB LDS,
// stage -> sync -> compute (A reg-prefetch for step kt loaded during kt-1's
// compute). Grid: bid = r*40 + nt*8 + x, stripe s = r*8+x -> all 5 nt-siblings
// share bid%8 (same XCD) so feat is fetched from HBM once per stripe.
// nt<4 -> h1 cols nt*128 (relu+b1); nt==4 -> jump (+b3+bj).
__global__ __launch_bounds__(256, 2) void k1(
    const float* __restrict__ feat, const short* __restrict__ wcatS,
    const float* __restrict__ b1, const float* __restrict__ b3,
    const float* __restrict__ bj,
    short* __restrict__ h1, short* __restrict__ jmp) {
  __shared__ __align__(16) short As[4 * 128 * 8];  // [ks=k/8][row][8] 8KB
  __shared__ __align__(16) short Bs[4 * 128 * 8];  // [ks][nloc][8]   8KB
  const int tid = threadIdx.x;
  const int lane = tid & 63, wid = tid >> 6;
  const int wr = wid >> 1, wc = wid & 1;
  const int l16 = lane & 15, lh = lane >> 4;
  const int bid = blockIdx.x;
  const int r = bid / 40, w40 = bid - r * 40, nt = w40 >> 3, x = w40 & 7;
  const int s = r * 8 + x;
  if (s >= MT) return;
  const int m0 = s * 128, n0 = nt * 128;

  f32x4 acc[4][4];
#pragma unroll
  for (int i = 0; i < 4; i++)
#pragma unroll
    for (int j = 0; j < 4; j++) acc[i][j] = (f32x4){0.f, 0.f, 0.f, 0.f};

  // A: thread t covers row ar=t>>1, k-half ah=(t&1)*16 of each 32-k step
  const int ar = tid >> 1;
  const int ah = (tid & 1) * 16;
  const bool aok = (m0 + ar) < N_NODES;
  const float* ap = feat + (size_t)(m0 + ar) * IN_DIM + ah;
  short* adst0 = &As[(((tid & 1) * 2) * 128 + ar) * 8];  // ks = (t&1)*2
  short* adst1 = adst0 + 1024;                           // ks+1

  // B: units u = s2*256+tid -> ks=u>>7, nloc=u&127; source from wcatS (coalesced)
  const short* bsrc[2];
  short* bdst[2];
#pragma unroll
  for (int s2 = 0; s2 < 2; s2++) {
    int u = s2 * 256 + tid;
    int ks = u >> 7, nloc = u & 127;
    bsrc[s2] = wcatS + ((size_t)ks * 640 + n0 + nloc) * 8;
    bdst[s2] = &Bs[u * 8];
  }

  for (int kt = 0; kt < IN_DIM / 32; ++kt) {
    f32x4 f0, f1, f2, f3;
    if (aok) {
      const f32x4* sp = (const f32x4*)(ap + kt * 32);
      f0 = sp[0]; f1 = sp[1]; f2 = sp[2]; f3 = sp[3];
    } else {
      f0 = f1 = f2 = f3 = (f32x4){0.f, 0.f, 0.f, 0.f};
    }
    __syncthreads();  // previous compute's LDS reads done
    bf16x8 s0, s1;
#pragma unroll
    for (int q = 0; q < 4; q++) {
      s0[q] = f2bf_hw(f0[q]); s0[q + 4] = f2bf_hw(f1[q]);
      s1[q] = f2bf_hw(f2[q]); s1[q + 4] = f2bf_hw(f3[q]);
    }
    *(bf16x8*)adst0 = s0;
    *(bf16x8*)adst1 = s1;
    gload_lds16(bsrc[0] + (size_t)kt * 20480, bdst[0]);  // 4*640*8 shorts per kt
    gload_lds16(bsrc[1] + (size_t)kt * 20480, bdst[1]);
    __syncthreads();  // staging visible
    bf16x8 a[4], b[4];
#pragma unroll
    for (int i = 0; i < 4; i++)
      a[i] = *(const bf16x8*)(&As[(lh * 128 + wr * 64 + i * 16 + l16) * 8]);
#pragma unroll
    for (int j = 0; j < 4; j++)
      b[j] = *(const bf16x8*)(&Bs[(lh * 128 + wc * 64 + j * 16 + l16) * 8]);
#pragma unroll
    for (int i = 0; i < 4; i++)
#pragma unroll
      for (int j = 0; j < 4; j++) acc[i][j] = mfma16(a[i], b[j], acc[i][j]);
  }

  if (nt < 4) {
    float bias[4];
#pragma unroll
    for (int j = 0; j < 4; j++) bias[j] = b1[n0 + wc * 64 + j * 16 + l16];
#pragma unroll
    for (int j = 0; j < 4; j++) {
      const int col = n0 + wc * 64 + j * 16 + l16;
#pragma unroll
      for (int i = 0; i < 4; i++) {
        const int row = m0 + wr * 64 + i * 16 + lh * 4;
#pragma unroll
        for (int rr = 0; rr < 4; rr++) {
          float v = acc[i][j][rr] + bias[j];
          v = v > 0.f ? v : 0.f;
          h1[(size_t)(row + rr) * HID + col] = f2bf(v);
        }
      }
    }
  } else {
    float bias[4];
#pragma unroll
    for (int j = 0; j < 4; j++) {
      int c = wc * 64 + j * 16 + l16;
      bias[j] = b3[c] + bj[c];
    }
#pragma unroll
    for (int j = 0; j < 4; j++) {
      const int c = wc * 64 + j * 16 + l16;
#pragma unroll
      for (int i = 0; i < 4; i++) {
        const int row = m0 + wr * 64 + i * 16 + lh * 4;
#pragma unroll
        for (int rr = 0; rr < 4; rr++)
          jmp[(size_t)(row + rr) * OUTD + c] = f2bf(acc[i][j][rr] + bias[j]);
      }
    }
  }
}

// ---- K2: same engine. h1[128] @ W2^T -> h2 (relu+b2). A via per-lane-row
// gload_lds into k-slot LDS (conflict-free reads); B from w2tS (coalesced).
// Grid: bid = r*32 + nt*8 + x -> 4 nt-siblings share XCD (h1 tile L2-shared).
__global__ __launch_bounds__(256, 2) void k2(
    const short* __restrict__ h1, const short* __restrict__ w2tS,
    const float* __restrict__ b2, short* __restrict__ h2) {
  __shared__ __align__(16) short As[4 * 128 * 8];  // [ks][row][8]
  __shared__ __align__(16) short Bs[4 * 128 * 8];  // [ks][nloc][8]
  const int tid = threadIdx.x;
  const int lane = tid & 63, wid = tid >> 6;
  const int wr = wid >> 1, wc = wid & 1;
  const int l16 = lane & 15, lh = lane >> 4;
  const int bid = blockIdx.x;
  const int r = bid >> 5, w32 = bid & 31, nt = w32 >> 3, x = w32 & 7;
  const int s = r * 8 + x;
  if (s >= MT) return;
  const int m0 = s * 128, n0 = nt * 128;

  f32x4 acc[4][4];
#pragma unroll
  for (int i = 0; i < 4; i++)
#pragma unroll
    for (int j = 0; j < 4; j++) acc[i][j] = (f32x4){0.f, 0.f, 0.f, 0.f};

  const short* asrc[2];
  const short* bsrc[2];
  short* adst[2];
  short* bdst[2];
#pragma unroll
  for (int s2 = 0; s2 < 2; s2++) {
    int u = s2 * 256 + tid;
    int ks = u >> 7, row = u & 127;
    asrc[s2] = h1 + (size_t)(m0 + row) * HID + ks * 8;    // per-lane row source
    bsrc[s2] = w2tS + ((size_t)ks * 512 + n0 + row) * 8;  // coalesced
    adst[s2] = &As[u * 8];
    bdst[s2] = &Bs[u * 8];
  }

  for (int kt = 0; kt < HID / 32; ++kt) {
    __syncthreads();
#pragma unroll
    for (int s2 = 0; s2 < 2; s2++) {
      gload_lds16(asrc[s2] + kt * 32, adst[s2]);
      gload_lds16(bsrc[s2] + (size_t)kt * 16384, bdst[s2]);  // 4*512*8 per kt
    }
    __syncthreads();
    bf16x8 a[4], b[4];
#pragma unroll
    for (int i = 0; i < 4; i++)
      a[i] = *(const bf16x8*)(&As[(lh * 128 + wr * 64 + i * 16 + l16) * 8]);
#pragma unroll
    for (int j = 0; j < 4; j++)
      b[j] = *(const bf16x8*)(&Bs[(lh * 128 + wc * 64 + j * 16 + l16) * 8]);
#pragma unroll
    for (int i = 0; i < 4; i++)
#pragma unroll
      for (int j = 0; j < 4; j++) acc[i][j] = mfma16(a[i], b[j], acc[i][j]);
  }

  float bias[4];
#pragma unroll
  for (int j = 0; j < 4; j++) bias[j] = b2[n0 + wc * 64 + j * 16 + l16];
#pragma unroll
  for (int j = 0; j < 4; j++) {
    const int col = n0 + wc * 64 + j * 16 + l16;
#pragma unroll
    for (int i = 0; i < 4; i++) {
      const int row = m0 + wr * 64 + i * 16 + lh * 4;
#pragma unroll
      for (int rr = 0; rr < 4; rr++) {
        float v = acc[i][j][rr] + bias[j];
        v = v > 0.f ? v : 0.f;
        h2[(size_t)(row + rr) * HID + col] = f2bf(v);
      }
    }
  }
}

// ---------------- K3: l_enc = h2@W3^T + jump; res = l_enc@g_enc^T; JS loss ----
__global__ __launch_bounds__(256, 2) void k3(
    const short* __restrict__ h2, const short* __restrict__ w3t,
    const short* __restrict__ jmp, const short* __restrict__ genc,
    const int* __restrict__ gid, float* __restrict__ partials) {
  __shared__ __align__(16) short As[128 * 32];
  __shared__ __align__(16) short Bs[128 * 32];
  __shared__ __align__(16) short Ll[128 * 128];  // l_enc, XOR-swizzled rows
  __shared__ int gids[128];
  __shared__ float sred[8];
  const int mt = blockIdx.x;
  const int m0 = mt * 128;
  const int tid = threadIdx.x;
  const int lane = tid & 63, wid = tid >> 6;
  const int wr = wid >> 1, wc = wid & 1;
  const int l16 = lane & 15, lh = lane >> 4;

  if (tid < 128) {
    int r = m0 + tid;
    gids[tid] = (r < N_NODES) ? gid[r] : -1;
  }

  f32x4 acc[4][4];
#pragma unroll
  for (int i = 0; i < 4; i++)
#pragma unroll
    for (int j = 0; j < 4; j++) acc[i][j] = (f32x4){0.f, 0.f, 0.f, 0.f};

  const short* ap0 = h2 + (size_t)(m0 + (tid >> 2)) * HID + (tid & 3) * 8;
  const short* ap1 = ap0 + (size_t)64 * HID;
  const short* bp0 = w3t + (size_t)(tid >> 2) * HID + (tid & 3) * 8;
  const short* bp1 = bp0 + (size_t)64 * HID;

  for (int kt = 0; kt < HID / 32; ++kt) {
    __syncthreads();
    gload_lds16(ap0 + kt * 32, &As[tid * 8]);
    gload_lds16(ap1 + kt * 32, &As[tid * 8 + 2048]);
    gload_lds16(bp0 + kt * 32, &Bs[tid * 8]);
    gload_lds16(bp1 + kt * 32, &Bs[tid * 8 + 2048]);
    __syncthreads();
    bf16x8 a[4], b[4];
#pragma unroll
    for (int i = 0; i < 4; i++)
      a[i] = *(const bf16x8*)(&As[(wr * 64 + i * 16 + l16) * 32 + lh * 8]);
#pragma unroll
    for (int j = 0; j < 4; j++)
      b[j] = *(const bf16x8*)(&Bs[(wc * 64 + j * 16 + l16) * 32 + lh * 8]);
#pragma unroll
    for (int i = 0; i < 4; i++)
#pragma unroll
      for (int j = 0; j < 4; j++) acc[i][j] = mfma16(a[i], b[j], acc[i][j]);
  }

  // epilogue: l_enc = acc + jump (jump already holds b3+bj) -> Ll (swizzled)
#pragma unroll
  for (int j = 0; j < 4; j++) {
    const int col = wc * 64 + j * 16 + l16;
#pragma unroll
    for (int i = 0; i < 4; i++) {
      const int rowb = wr * 64 + i * 16 + lh * 4;
#pragma unroll
      for (int r = 0; r < 4; r++) {
        const int row = rowb + r;
        float v = acc[i][j][r] + bf2f(jmp[(size_t)(m0 + row) * OUTD + col]);
        unsigned byte = (unsigned)row * 256u +
                        (((unsigned)col * 2u) ^ (((unsigned)(row & 7)) << 4));
        *(short*)((char*)Ll + byte) = f2bf(v);
      }
    }
  }
  __syncthreads();

  int myg[4][4];
#pragma unroll
  for (int i = 0; i < 4; i++)
#pragma unroll
    for (int r = 0; r < 4; r++) myg[i][r] = gids[wr * 64 + i * 16 + lh * 4 + r];

  float pacc = 0.f, nacc = 0.f;
  for (int nc = 0; nc < 4; ++nc) {
    f32x4 a2[4][4];
#pragma unroll
    for (int i = 0; i < 4; i++)
#pragma unroll
      for (int j = 0; j < 4; j++) a2[i][j] = (f32x4){0.f, 0.f, 0.f, 0.f};
#pragma unroll
    for (int ks = 0; ks < 4; ++ks) {
      bf16x8 af[4], bg[4];
#pragma unroll
      for (int i = 0; i < 4; i++) {
        const int row = wr * 64 + i * 16 + l16;
        unsigned byte = (unsigned)row * 256u +
                        (((unsigned)(ks * 64 + lh * 16)) ^ (((unsigned)(row & 7)) << 4));
        af[i] = *(const bf16x8*)((const char*)Ll + byte);
      }
#pragma unroll
      for (int j = 0; j < 4; j++) {
        const int g = nc * 128 + wc * 64 + j * 16 + l16;
        bg[j] = *(const bf16x8*)(genc + (size_t)g * OUTD + ks * 32 + lh * 8);
      }
#pragma unroll
      for (int i = 0; i < 4; i++)
#pragma unroll
        for (int j = 0; j < 4; j++) a2[i][j] = mfma16(af[i], bg[j], a2[i][j]);
    }
#pragma unroll
    for (int j = 0; j < 4; j++) {
      const int g = nc * 128 + wc * 64 + j * 16 + l16;
#pragma unroll
      for (int i = 0; i < 4; i++) {
#pragma unroll
        for (int r = 0; r < 4; r++) {
          float rv = a2[i][j][r];
          int gr = myg[i][r];
          float t = __expf(-fabsf(rv));
          float lg = __logf(1.f + t);
          if (gr == g)
            pacc += LOG2F_ - (fmaxf(-rv, 0.f) + lg);
          else if (gr >= 0)
            nacc += (fmaxf(rv, 0.f) + lg) - LOG2F_;
        }
      }
    }
  }

#pragma unroll
  for (int o = 32; o; o >>= 1) {
    pacc += __shfl_down(pacc, o);
    nacc += __shfl_down(nacc, o);
  }
  if (lane == 0) { sred[wid] = pacc; sred[4 + wid] = nacc; }
  __syncthreads();
  if (tid == 0) {
    partials[2 * mt] = sred[0] + sred[1] + sred[2] + sred[3];
    partials[2 * mt + 1] = sred[4] + sred[5] + sred[6] + sred[7];
  }
}

// ---------------- K4: deterministic final reduction ---------------------------
__global__ void k4(const float* __restrict__ partials, float* __restrict__ out) {
  const int tid = threadIdx.x;
  float p = 0.f, n = 0.f;
  for (int i = tid; i < MT; i += 256) {
    p += partials[2 * i];
    n += partials[2 * i + 1];
  }
#pragma unroll
  for (int o = 32; o; o >>= 1) {
    p += __shfl_down(p, o);
    n += __shfl_down(n, o);
  }
  __shared__ float sp[4], sn[4];
  const int wid = tid >> 6, lane = tid & 63;
  if (lane == 0) { sp[wid] = p; sn[wid] = n; }
  __syncthreads();
  if (tid == 0) {
    float P = sp[0] + sp[1] + sp[2] + sp[3];
    float Nn = sn[0] + sn[1] + sn[2] + sn[3];
    out[0] = Nn / (100000.0f * 511.0f) - P / 100000.0f;
  }
}

extern "C" void kernel_launch(void* const* d_in, const int* in_sizes, int n_in,
                              void* d_out, int out_size, void* d_ws, size_t ws_size,
                              hipStream_t stream) {
  const float* feat = (const float*)d_in[0];
  const float* genc_f = (const float*)d_in[1];
  const int* gid = (const int*)d_in[2];
  const float* W1 = (const float*)d_in[3];
  const float* b1 = (const float*)d_in[4];
  const float* W2 = (const float*)d_in[5];
  const float* b2 = (const float*)d_in[6];
  const float* W3 = (const float*)d_in[7];
  const float* b3 = (const float*)d_in[8];
  const float* Wj = (const float*)d_in[9];
  const float* bj = (const float*)d_in[10];
  float* out = (float*)d_out;

  char* ws = (char*)d_ws;
  float* partials = (float*)ws;                       // 782*2 f32
  short* wcatS = (short*)(ws + 8192);                 // [256][640][8] k-slot
  short* w2tS = wcatS + (size_t)640 * 2048;           // [64][512][8] k-slot
  short* w3t = w2tS + (size_t)512 * 512;              // [128][512] row-major
  short* gencb = w3t + (size_t)128 * 512;             // [512][128] row-major
  short* h1 = gencb + (size_t)512 * 128;              // [MPAD][512]
  short* h2 = h1 + (size_t)MPAD * 512;                // [MPAD][512]
  short* jmp = h2 + (size_t)MPAD * 512;               // [MPAD][128]

  kprep<<<6656, 256, 0, stream>>>(W1, Wj, W2, W3, genc_f, wcatS, w2tS, w3t, gencb);
  k1<<<98 * 40, 256, 0, stream>>>(feat, wcatS, b1, b3, bj, h1, jmp);
  k2<<<98 * 32, 256, 0, stream>>>(h1, w2tS, b2, h2);
  k3<<<MT, 256, 0, stream>>>(h2, w3t, jmp, gencb, gid, partials);
  k4<<<1, 256, 0, stream>>>(partials, out);
}